// Round 1
// baseline (1565.812 us; speedup 1.0000x reference)
//
#include <hip/hip_runtime.h>

#define BSZ 16384

// ---------------- GEMM: C = act(A @ W^T + bias) ----------------
// A: (M,K) row-major, W: (N,K) row-major, bias: (N), C: (M,N)
// Requires: M,N multiples of 64; K multiple of 16.
__global__ __launch_bounds__(256) void gemm_bias_act(
    const float* __restrict__ A, const float* __restrict__ W,
    const float* __restrict__ bias, float* __restrict__ C,
    int M, int N, int K, int relu)
{
    __shared__ float As[16][68];
    __shared__ float Ws[16][68];
    const int tid = threadIdx.x;
    const int bm = blockIdx.y << 6;
    const int bn = blockIdx.x << 6;
    const int row = tid >> 2;        // 0..63
    const int kq  = (tid & 3) << 2;  // 0,4,8,12
    const int tx = tid & 15;
    const int ty = tid >> 4;
    float acc[4][4] = {};
    const float* Ap = A + (size_t)(bm + row) * K + kq;
    const float* Wp = W + (size_t)(bn + row) * K + kq;
    for (int k0 = 0; k0 < K; k0 += 16) {
        const float4 av = *(const float4*)(Ap + k0);
        const float4 wv = *(const float4*)(Wp + k0);
        __syncthreads();
        As[kq + 0][row] = av.x; As[kq + 1][row] = av.y;
        As[kq + 2][row] = av.z; As[kq + 3][row] = av.w;
        Ws[kq + 0][row] = wv.x; Ws[kq + 1][row] = wv.y;
        Ws[kq + 2][row] = wv.z; Ws[kq + 3][row] = wv.w;
        __syncthreads();
        #pragma unroll
        for (int kk = 0; kk < 16; ++kk) {
            const float4 a = *(const float4*)&As[kk][ty << 2];
            const float4 w = *(const float4*)&Ws[kk][tx << 2];
            const float aa[4] = {a.x, a.y, a.z, a.w};
            const float ww[4] = {w.x, w.y, w.z, w.w};
            #pragma unroll
            for (int i = 0; i < 4; ++i)
                #pragma unroll
                for (int j = 0; j < 4; ++j)
                    acc[i][j] += aa[i] * ww[j];
        }
    }
    const int c = bn + (tx << 2);
    const float4 bv = *(const float4*)(bias + c);
    const float bb[4] = {bv.x, bv.y, bv.z, bv.w};
    #pragma unroll
    for (int i = 0; i < 4; ++i) {
        const int r = bm + (ty << 2) + i;
        float v0 = acc[i][0] + bb[0];
        float v1 = acc[i][1] + bb[1];
        float v2 = acc[i][2] + bb[2];
        float v3 = acc[i][3] + bb[3];
        if (relu) {
            v0 = fmaxf(v0, 0.f); v1 = fmaxf(v1, 0.f);
            v2 = fmaxf(v2, 0.f); v3 = fmaxf(v3, 0.f);
        }
        float4 o; o.x = v0; o.y = v1; o.z = v2; o.w = v3;
        *(float4*)(C + (size_t)r * N + c) = o;
    }
}

// ---------------- codebook norms ----------------
__global__ __launch_bounds__(256) void cb_norms(
    const float* __restrict__ cb, float* __restrict__ cbn, int CB)
{
    int e = blockIdx.x * 256 + threadIdx.x;
    if (e < CB) {
        const float4* p = (const float4*)(cb + ((size_t)e << 6));
        float s = 0.f;
        #pragma unroll
        for (int c = 0; c < 16; ++c) {
            float4 v = p[c];
            s += v.x * v.x + v.y * v.y + v.z * v.z + v.w * v.w;
        }
        cbn[e] = s;
    }
}

// ---------------- VQ argmin + gather ----------------
// Block: 64 samples, full codebook sweep in 128-entry LDS tiles.
// dist = |cb|^2 - 2 * ze.cb  (|ze|^2 constant per sample, argmin-invariant)
__global__ __launch_bounds__(256) void vq_argmin(
    const float* __restrict__ ze, const float* __restrict__ cb,
    const float* __restrict__ cbn, float* __restrict__ zq, int CB)
{
    __shared__ float zs[64][68];
    __shared__ float cs[128 * 64];   // XOR-swizzled rows of 16 float4 chunks
    __shared__ float cn[128];
    __shared__ int   idxs[64];
    const int tid = threadIdx.x;
    const size_t s0 = (size_t)blockIdx.x * 64;

    for (int t = tid; t < 64 * 64; t += 256) {
        int s = t >> 6, d = t & 63;
        zs[s][d] = ze[(s0 + s) * 64 + d];
    }

    const int ti = tid >> 4;   // sample group 0..15 (4 samples each)
    const int tj = tid & 15;   // entry group 0..15 (8 entries each)
    float bestd[4];
    int   besti[4];
    #pragma unroll
    for (int i = 0; i < 4; ++i) { bestd[i] = 3.4e38f; besti[i] = 0x7fffffff; }

    for (int e0 = 0; e0 < CB; e0 += 128) {
        __syncthreads();
        // load codebook tile, swizzle chunk index by (e>>3) to kill bank conflicts
        #pragma unroll
        for (int k = 0; k < 8; ++k) {
            int t4 = tid + k * 256;          // 0..2047 float4s
            int e = t4 >> 4, c = t4 & 15;
            const float4 v = *(const float4*)(cb + ((size_t)(e0 + e) << 6) + (c << 2));
            *(float4*)&cs[(e << 6) + (((c ^ (e >> 3)) & 15) << 2)] = v;
        }
        if (tid < 128) cn[tid] = cbn[e0 + tid];
        __syncthreads();

        float acc[4][8] = {};
        #pragma unroll
        for (int c = 0; c < 16; ++c) {
            float4 a[4];
            #pragma unroll
            for (int i = 0; i < 4; ++i)
                a[i] = *(const float4*)&zs[(ti << 2) + i][c << 2];
            #pragma unroll
            for (int j = 0; j < 8; ++j) {
                const int e = (tj << 3) + j;
                const float4 b = *(const float4*)&cs[(e << 6) + (((c ^ (e >> 3)) & 15) << 2)];
                #pragma unroll
                for (int i = 0; i < 4; ++i)
                    acc[i][j] += a[i].x * b.x + a[i].y * b.y + a[i].z * b.z + a[i].w * b.w;
            }
        }
        #pragma unroll
        for (int j = 0; j < 8; ++j) {
            const int e = (tj << 3) + j;
            const float nn = cn[e];
            #pragma unroll
            for (int i = 0; i < 4; ++i) {
                const float dist = nn - 2.0f * acc[i][j];
                // strict <  →  first (lowest-index) min kept within a thread
                if (dist < bestd[i]) { bestd[i] = dist; besti[i] = e0 + e; }
            }
        }
    }
    // reduce across the 16 entry-lanes (contiguous lanes within a wave)
    #pragma unroll
    for (int off = 1; off < 16; off <<= 1) {
        #pragma unroll
        for (int i = 0; i < 4; ++i) {
            float od = __shfl_xor(bestd[i], off, 64);
            int   oi = __shfl_xor(besti[i], off, 64);
            if (od < bestd[i] || (od == bestd[i] && oi < besti[i])) {
                bestd[i] = od; besti[i] = oi;
            }
        }
    }
    if (tj == 0) {
        #pragma unroll
        for (int i = 0; i < 4; ++i) idxs[(ti << 2) + i] = besti[i];
    }
    __syncthreads();
    for (int t = tid; t < 64 * 64; t += 256) {
        int s = t >> 6, d = t & 63;
        zq[(s0 + s) * 64 + d] = cb[((size_t)idxs[s] << 6) + d];
    }
}

// ---------------- losses ----------------
// commit += mean((ze - zq)^2); vq += mean((zq - (ze + att))^2) (att may be null)
__global__ __launch_bounds__(256) void loss_kernel(
    const float* __restrict__ ze, const float* __restrict__ zq,
    const float* __restrict__ att, float* __restrict__ vq_out,
    float* __restrict__ commit_out, int n, float inv)
{
    float cs = 0.f, vs = 0.f;
    for (int t = blockIdx.x * 256 + threadIdx.x; t < n; t += gridDim.x * 256) {
        float e = ze[t], q = zq[t];
        float dc = e - q;
        cs += dc * dc;
        float za = att ? (e + att[t]) : e;
        float dv = q - za;
        vs += dv * dv;
    }
    #pragma unroll
    for (int off = 32; off; off >>= 1) {
        cs += __shfl_down(cs, off, 64);
        vs += __shfl_down(vs, off, 64);
    }
    __shared__ float sc[4], sv[4];
    int lane = threadIdx.x & 63, w = threadIdx.x >> 6;
    if (lane == 0) { sc[w] = cs; sv[w] = vs; }
    __syncthreads();
    if (threadIdx.x == 0) {
        float c = sc[0] + sc[1] + sc[2] + sc[3];
        float v = sv[0] + sv[1] + sv[2] + sv[3];
        atomicAdd(commit_out, c * inv);
        atomicAdd(vq_out, v * inv);
    }
}

static inline void gemm(const float* A, const float* W, const float* b, float* C,
                        int M, int N, int K, int relu, hipStream_t s)
{
    dim3 g(N >> 6, M >> 6);
    hipLaunchKernelGGL(gemm_bias_act, g, dim3(256), 0, s, A, W, b, C, M, N, K, relu);
}

extern "C" void kernel_launch(void* const* d_in, const int* in_sizes, int n_in,
                              void* d_out, int out_size, void* d_ws, size_t ws_size,
                              hipStream_t stream)
{
    const int CB_SIZES[3] = {2048, 4096, 4096};
    const float* x[3] = {(const float*)d_in[0], (const float*)d_in[1], (const float*)d_in[2]};

    float* ws  = (float*)d_ws;
    float* h1  = ws;                       // B*256
    float* h2  = h1 + (size_t)BSZ * 256;   // B*256
    float* z_e = h2 + (size_t)BSZ * 256;   // B*64
    float* zq0 = z_e + (size_t)BSZ * 64;   // B*64
    float* zq1 = zq0 + (size_t)BSZ * 64;   // B*64
    float* vv  = zq1 + (size_t)BSZ * 64;   // B*64
    float* att = vv  + (size_t)BSZ * 64;   // B*64
    float* cbn = att + (size_t)BSZ * 64;   // 4096

    float* out = (float*)d_out;
    float* vq_loss = out + (size_t)3 * BSZ * 512;
    float* commit  = vq_loss + 1;
    hipMemsetAsync(vq_loss, 0, 2 * sizeof(float), stream);

    const float* zq_prev = nullptr;
    for (int l = 0; l < 3; ++l) {
        const int base = 3 + 13 * l;
        const float* ew1 = (const float*)d_in[base + 0];
        const float* eb1 = (const float*)d_in[base + 1];
        const float* ew2 = (const float*)d_in[base + 2];
        const float* eb2 = (const float*)d_in[base + 3];
        const float* ew3 = (const float*)d_in[base + 4];
        const float* eb3 = (const float*)d_in[base + 5];
        const float* dw1 = (const float*)d_in[base + 6];
        const float* db1 = (const float*)d_in[base + 7];
        const float* dw2 = (const float*)d_in[base + 8];
        const float* db2 = (const float*)d_in[base + 9];
        const float* dw3 = (const float*)d_in[base + 10];
        const float* db3 = (const float*)d_in[base + 11];
        const float* cb  = (const float*)d_in[base + 12];
        const int CB = CB_SIZES[l];

        // encoder
        gemm(x[l], ew1, eb1, h1, BSZ, 256, 512, 1, stream);
        gemm(h1, ew2, eb2, h2, BSZ, 256, 256, 1, stream);
        gemm(h2, ew3, eb3, z_e, BSZ, 64, 256, 0, stream);

        // quantize
        float* zq = (l & 1) ? zq1 : zq0;
        hipLaunchKernelGGL(cb_norms, dim3((CB + 255) / 256), dim3(256), 0, stream, cb, cbn, CB);
        hipLaunchKernelGGL(vq_argmin, dim3(BSZ / 64), dim3(256), 0, stream, z_e, cb, cbn, zq, CB);

        // attention (l > 0): att = (zq_prev @ wv^T + bv) @ ow^T + ob
        const float* attp = nullptr;
        if (l > 0) {
            const int ab = 42 + 4 * (l - 1);
            const float* iw = (const float*)d_in[ab + 0];
            const float* ib = (const float*)d_in[ab + 1];
            const float* ow = (const float*)d_in[ab + 2];
            const float* ob = (const float*)d_in[ab + 3];
            gemm(zq_prev, iw + 128 * 64, ib + 128, vv, BSZ, 64, 64, 0, stream);
            gemm(vv, ow, ob, att, BSZ, 64, 64, 0, stream);
            attp = att;
        }

        // losses
        hipLaunchKernelGGL(loss_kernel, dim3(512), dim3(256), 0, stream,
                           z_e, zq, attp, vq_loss, commit,
                           BSZ * 64, 1.0f / (float)(BSZ * 64));

        // decoder (z_q straight-through == z_q in forward)
        gemm(zq, dw1, db1, h1, BSZ, 256, 64, 1, stream);
        gemm(h1, dw2, db2, h2, BSZ, 256, 256, 1, stream);
        gemm(h2, dw3, db3, out + (size_t)l * BSZ * 512, BSZ, 512, 256, 0, stream);

        zq_prev = zq;
    }
}

// Round 2
// 933.273 us; speedup vs baseline: 1.6778x; 1.6778x over previous
//
#include <hip/hip_runtime.h>

#define BSZ 16384

typedef __attribute__((ext_vector_type(8))) short bf16x8;
typedef __attribute__((ext_vector_type(4))) float f32x4;

__device__ inline unsigned short f2bf(float x) {
    unsigned u = __float_as_uint(x);
    u += 0x7fffu + ((u >> 16) & 1u);
    return (unsigned short)(u >> 16);
}
__device__ inline float bf2f(unsigned short h) {
    return __uint_as_float(((unsigned)h) << 16);
}

// ---------------- MFMA GEMM: C = act(A @ W^T + bias) ----------------
// A: (M,K) fp32 row-major, W: (N,K) fp32 row-major, bias fp32 (N), C fp32 (M,N)
// SPLIT=1: 3-term split-bf16 (fp32-grade), SPLIT=0: plain bf16.
// Macro-tile 128(M) x 64(N), BK=32. Block = 256 threads = 4 waves;
// wave w computes rows [32w,32w+32) x all 64 cols.
template<int SPLIT>
__global__ __launch_bounds__(256) void gemm_mfma(
    const float* __restrict__ A, const float* __restrict__ W,
    const float* __restrict__ bias, float* __restrict__ C,
    int M, int N, int K, int relu)
{
    __shared__ short lds[SPLIT ? 15360 : 7680];
    const int AH0 = 0;
    const int AL0 = SPLIT ? 5120 : 0;
    const int WH0 = SPLIT ? 10240 : 5120;
    const int WL0 = SPLIT ? 12800 : 0;
    const int tid = threadIdx.x;
    const int m0 = blockIdx.y << 7;
    const int n0 = blockIdx.x << 6;
    const int lane = tid & 63, wv = tid >> 6;
    const int q = lane >> 4, c16 = lane & 15;

    f32x4 acc[2][4];
    #pragma unroll
    for (int mt = 0; mt < 2; ++mt)
        #pragma unroll
        for (int nt = 0; nt < 4; ++nt)
            acc[mt][nt] = (f32x4){0.f, 0.f, 0.f, 0.f};

    for (int k0 = 0; k0 < K; k0 += 32) {
        // ---- stage A tile (128 x 32 fp32 -> bf16 hi[/lo]) ----
        #pragma unroll
        for (int i = 0; i < 4; ++i) {
            const int c = tid + (i << 8);        // 0..1023 chunks of 4 floats
            const int row = c >> 3, col = c & 7;
            const float4 v = *(const float4*)(A + (size_t)(m0 + row) * K + k0 + (col << 2));
            ushort4 h;
            h.x = f2bf(v.x); h.y = f2bf(v.y); h.z = f2bf(v.z); h.w = f2bf(v.w);
            *(ushort4*)&lds[AH0 + row * 40 + (col << 2)] = h;
            if (SPLIT) {
                ushort4 l;
                l.x = f2bf(v.x - bf2f(h.x)); l.y = f2bf(v.y - bf2f(h.y));
                l.z = f2bf(v.z - bf2f(h.z)); l.w = f2bf(v.w - bf2f(h.w));
                *(ushort4*)&lds[AL0 + row * 40 + (col << 2)] = l;
            }
        }
        // ---- stage W tile (64 x 32) ----
        #pragma unroll
        for (int i = 0; i < 2; ++i) {
            const int c = tid + (i << 8);        // 0..511
            const int row = c >> 3, col = c & 7;
            const float4 v = *(const float4*)(W + (size_t)(n0 + row) * K + k0 + (col << 2));
            ushort4 h;
            h.x = f2bf(v.x); h.y = f2bf(v.y); h.z = f2bf(v.z); h.w = f2bf(v.w);
            *(ushort4*)&lds[WH0 + row * 40 + (col << 2)] = h;
            if (SPLIT) {
                ushort4 l;
                l.x = f2bf(v.x - bf2f(h.x)); l.y = f2bf(v.y - bf2f(h.y));
                l.z = f2bf(v.z - bf2f(h.z)); l.w = f2bf(v.w - bf2f(h.w));
                *(ushort4*)&lds[WL0 + row * 40 + (col << 2)] = l;
            }
        }
        __syncthreads();

        bf16x8 ah[2], al[2], bh[4], bl[4];
        #pragma unroll
        for (int mt = 0; mt < 2; ++mt) {
            const int r = (wv << 5) + (mt << 4) + c16;
            ah[mt] = *(const bf16x8*)&lds[AH0 + r * 40 + (q << 3)];
            if (SPLIT) al[mt] = *(const bf16x8*)&lds[AL0 + r * 40 + (q << 3)];
        }
        #pragma unroll
        for (int nt = 0; nt < 4; ++nt) {
            const int r = (nt << 4) + c16;
            bh[nt] = *(const bf16x8*)&lds[WH0 + r * 40 + (q << 3)];
            if (SPLIT) bl[nt] = *(const bf16x8*)&lds[WL0 + r * 40 + (q << 3)];
        }
        #pragma unroll
        for (int nt = 0; nt < 4; ++nt)
            #pragma unroll
            for (int mt = 0; mt < 2; ++mt) {
                acc[mt][nt] = __builtin_amdgcn_mfma_f32_16x16x32_bf16(ah[mt], bh[nt], acc[mt][nt], 0, 0, 0);
                if (SPLIT) {
                    acc[mt][nt] = __builtin_amdgcn_mfma_f32_16x16x32_bf16(ah[mt], bl[nt], acc[mt][nt], 0, 0, 0);
                    acc[mt][nt] = __builtin_amdgcn_mfma_f32_16x16x32_bf16(al[mt], bh[nt], acc[mt][nt], 0, 0, 0);
                }
            }
        __syncthreads();
    }

    // ---- epilogue: C/D layout col=lane&15, row=(lane>>4)*4+reg ----
    #pragma unroll
    for (int nt = 0; nt < 4; ++nt) {
        const int gcol = n0 + (nt << 4) + c16;
        const float bb = bias[gcol];
        #pragma unroll
        for (int mt = 0; mt < 2; ++mt)
            #pragma unroll
            for (int r = 0; r < 4; ++r) {
                const int grow = m0 + (wv << 5) + (mt << 4) + (q << 2) + r;
                float v = acc[mt][nt][r] + bb;
                if (relu) v = fmaxf(v, 0.f);
                C[(size_t)grow * N + gcol] = v;
            }
    }
}

// ---------------- codebook norms ----------------
__global__ __launch_bounds__(256) void cb_norms(
    const float* __restrict__ cb, float* __restrict__ cbn, int CB)
{
    int e = blockIdx.x * 256 + threadIdx.x;
    if (e < CB) {
        const float4* p = (const float4*)(cb + ((size_t)e << 6));
        float s = 0.f;
        #pragma unroll
        for (int c = 0; c < 16; ++c) {
            float4 v = p[c];
            s += v.x * v.x + v.y * v.y + v.z * v.z + v.w * v.w;
        }
        cbn[e] = s;
    }
}

// ---------------- VQ argmin via split-bf16 MFMA + gather ----------------
// Block: 64 samples (4 waves; wave w owns 16-col strip of each 64-entry tile).
// dist = |cb|^2 - 2 * ze.cb ; 3-term split-bf16 MFMA gives fp32-grade dots.
__global__ __launch_bounds__(256) void vq_mfma(
    const float* __restrict__ ze, const float* __restrict__ cb,
    const float* __restrict__ cbn, float* __restrict__ zq, int CB)
{
    __shared__ float zs[64][68];
    __shared__ short csh[64][72];
    __shared__ short csl[64][72];
    __shared__ float cn[64];
    __shared__ float bd_s[64][4];
    __shared__ int   bi_s[64][4];
    __shared__ int   idxs[64];
    const int tid = threadIdx.x;
    const int lane = tid & 63, wv = tid >> 6;
    const int q = lane >> 4, c16 = lane & 15;
    const size_t s0 = (size_t)blockIdx.x << 6;

    // stage z (64 x 64 fp32)
    #pragma unroll
    for (int i = 0; i < 4; ++i) {
        const int c = tid + (i << 8);
        const int row = c >> 4, col = c & 15;
        *(float4*)&zs[row][col << 2] = *(const float4*)(ze + (s0 + row) * 64 + (col << 2));
    }
    __syncthreads();

    // build A-fragments in registers (hi/lo), reused across the whole sweep
    bf16x8 ah[4][2], al[4][2];
    #pragma unroll
    for (int mt = 0; mt < 4; ++mt)
        #pragma unroll
        for (int ks = 0; ks < 2; ++ks) {
            const float* p = &zs[(mt << 4) + c16][(ks << 5) + (q << 3)];
            bf16x8 h, l;
            #pragma unroll
            for (int j = 0; j < 8; ++j) {
                const unsigned short hh = f2bf(p[j]);
                h[j] = (short)hh;
                l[j] = (short)f2bf(p[j] - bf2f(hh));
            }
            ah[mt][ks] = h;
            al[mt][ks] = l;
        }

    float bd[4][4];
    int   bi[4][4];
    #pragma unroll
    for (int mt = 0; mt < 4; ++mt)
        #pragma unroll
        for (int r = 0; r < 4; ++r) { bd[mt][r] = 3.4e38f; bi[mt][r] = 0x7fffffff; }

    for (int e0 = 0; e0 < CB; e0 += 64) {
        __syncthreads();   // protect LDS from previous tile's readers
        // stage cb tile (64 entries x 64 dims fp32 -> hi/lo bf16)
        #pragma unroll
        for (int i = 0; i < 4; ++i) {
            const int c = tid + (i << 8);
            const int row = c >> 4, col = c & 15;
            const float4 v = *(const float4*)(cb + (size_t)(e0 + row) * 64 + (col << 2));
            ushort4 h, l;
            h.x = f2bf(v.x); h.y = f2bf(v.y); h.z = f2bf(v.z); h.w = f2bf(v.w);
            l.x = f2bf(v.x - bf2f(h.x)); l.y = f2bf(v.y - bf2f(h.y));
            l.z = f2bf(v.z - bf2f(h.z)); l.w = f2bf(v.w - bf2f(h.w));
            *(ushort4*)&csh[row][col << 2] = h;
            *(ushort4*)&csl[row][col << 2] = l;
        }
        if (tid < 64) cn[tid] = cbn[e0 + tid];
        __syncthreads();

        f32x4 acc[4];
        #pragma unroll
        for (int mt = 0; mt < 4; ++mt) acc[mt] = (f32x4){0.f, 0.f, 0.f, 0.f};
        #pragma unroll
        for (int ks = 0; ks < 2; ++ks) {
            const int brow = (wv << 4) + c16;
            const bf16x8 bh = *(const bf16x8*)&csh[brow][(ks << 5) + (q << 3)];
            const bf16x8 bl = *(const bf16x8*)&csl[brow][(ks << 5) + (q << 3)];
            #pragma unroll
            for (int mt = 0; mt < 4; ++mt) {
                acc[mt] = __builtin_amdgcn_mfma_f32_16x16x32_bf16(ah[mt][ks], bh, acc[mt], 0, 0, 0);
                acc[mt] = __builtin_amdgcn_mfma_f32_16x16x32_bf16(ah[mt][ks], bl, acc[mt], 0, 0, 0);
                acc[mt] = __builtin_amdgcn_mfma_f32_16x16x32_bf16(al[mt][ks], bh, acc[mt], 0, 0, 0);
            }
        }
        const int   eidx = e0 + (wv << 4) + c16;
        const float nn   = cn[(wv << 4) + c16];
        #pragma unroll
        for (int mt = 0; mt < 4; ++mt)
            #pragma unroll
            for (int r = 0; r < 4; ++r) {
                const float dist = nn - 2.0f * acc[mt][r];
                // strict < + increasing e0 sweep => first (lowest) index kept
                if (dist < bd[mt][r]) { bd[mt][r] = dist; bi[mt][r] = eidx; }
            }
    }

    // reduce across the 16 col-lanes (stay within quad: xor masks < 16)
    #pragma unroll
    for (int off = 1; off < 16; off <<= 1)
        #pragma unroll
        for (int mt = 0; mt < 4; ++mt)
            #pragma unroll
            for (int r = 0; r < 4; ++r) {
                const float od = __shfl_xor(bd[mt][r], off, 64);
                const int   oi = __shfl_xor(bi[mt][r], off, 64);
                if (od < bd[mt][r] || (od == bd[mt][r] && oi < bi[mt][r])) {
                    bd[mt][r] = od; bi[mt][r] = oi;
                }
            }
    if (c16 == 0)
        #pragma unroll
        for (int mt = 0; mt < 4; ++mt)
            #pragma unroll
            for (int r = 0; r < 4; ++r) {
                const int row = (mt << 4) + (q << 2) + r;
                bd_s[row][wv] = bd[mt][r];
                bi_s[row][wv] = bi[mt][r];
            }
    __syncthreads();
    if (tid < 64) {
        float best = bd_s[tid][0];
        int   bidx = bi_s[tid][0];
        #pragma unroll
        for (int w2 = 1; w2 < 4; ++w2) {
            const float d = bd_s[tid][w2];
            const int   i2 = bi_s[tid][w2];
            if (d < best || (d == best && i2 < bidx)) { best = d; bidx = i2; }
        }
        idxs[tid] = bidx;
    }
    __syncthreads();
    for (int t = tid; t < 64 * 64; t += 256) {
        const int s = t >> 6, d = t & 63;
        zq[(s0 + s) * 64 + d] = cb[(size_t)idxs[s] * 64 + d];
    }
}

// ---------------- losses ----------------
__global__ __launch_bounds__(256) void loss_kernel(
    const float* __restrict__ ze, const float* __restrict__ zq,
    const float* __restrict__ att, float* __restrict__ vq_out,
    float* __restrict__ commit_out, int n, float inv)
{
    float cs = 0.f, vs = 0.f;
    for (int t = blockIdx.x * 256 + threadIdx.x; t < n; t += gridDim.x * 256) {
        float e = ze[t], qv = zq[t];
        float dc = e - qv;
        cs += dc * dc;
        float za = att ? (e + att[t]) : e;
        float dv = qv - za;
        vs += dv * dv;
    }
    #pragma unroll
    for (int off = 32; off; off >>= 1) {
        cs += __shfl_down(cs, off, 64);
        vs += __shfl_down(vs, off, 64);
    }
    __shared__ float sc[4], sv[4];
    int lane = threadIdx.x & 63, w = threadIdx.x >> 6;
    if (lane == 0) { sc[w] = cs; sv[w] = vs; }
    __syncthreads();
    if (threadIdx.x == 0) {
        float c = sc[0] + sc[1] + sc[2] + sc[3];
        float v = sv[0] + sv[1] + sv[2] + sv[3];
        atomicAdd(commit_out, c * inv);
        atomicAdd(vq_out, v * inv);
    }
}

template<int SPLIT>
static inline void gemm(const float* A, const float* W, const float* b, float* C,
                        int M, int N, int K, int relu, hipStream_t s)
{
    dim3 g(N >> 6, M >> 7);
    hipLaunchKernelGGL((gemm_mfma<SPLIT>), g, dim3(256), 0, s, A, W, b, C, M, N, K, relu);
}

extern "C" void kernel_launch(void* const* d_in, const int* in_sizes, int n_in,
                              void* d_out, int out_size, void* d_ws, size_t ws_size,
                              hipStream_t stream)
{
    const int CB_SIZES[3] = {2048, 4096, 4096};
    const float* x[3] = {(const float*)d_in[0], (const float*)d_in[1], (const float*)d_in[2]};

    float* ws  = (float*)d_ws;
    float* h1  = ws;                       // B*256
    float* h2  = h1 + (size_t)BSZ * 256;   // B*256
    float* z_e = h2 + (size_t)BSZ * 256;   // B*64
    float* zq0 = z_e + (size_t)BSZ * 64;   // B*64
    float* zq1 = zq0 + (size_t)BSZ * 64;   // B*64
    float* vv  = zq1 + (size_t)BSZ * 64;   // B*64
    float* att = vv  + (size_t)BSZ * 64;   // B*64
    float* cbn = att + (size_t)BSZ * 64;   // 4096

    float* out = (float*)d_out;
    float* vq_loss = out + (size_t)3 * BSZ * 512;
    float* commit  = vq_loss + 1;
    hipMemsetAsync(vq_loss, 0, 2 * sizeof(float), stream);

    const float* zq_prev = nullptr;
    for (int l = 0; l < 3; ++l) {
        const int base = 3 + 13 * l;
        const float* ew1 = (const float*)d_in[base + 0];
        const float* eb1 = (const float*)d_in[base + 1];
        const float* ew2 = (const float*)d_in[base + 2];
        const float* eb2 = (const float*)d_in[base + 3];
        const float* ew3 = (const float*)d_in[base + 4];
        const float* eb3 = (const float*)d_in[base + 5];
        const float* dw1 = (const float*)d_in[base + 6];
        const float* db1 = (const float*)d_in[base + 7];
        const float* dw2 = (const float*)d_in[base + 8];
        const float* db2 = (const float*)d_in[base + 9];
        const float* dw3 = (const float*)d_in[base + 10];
        const float* db3 = (const float*)d_in[base + 11];
        const float* cb  = (const float*)d_in[base + 12];
        const int CB = CB_SIZES[l];

        // encoder (split-bf16: z_e must be fp32-grade for the argmin)
        gemm<1>(x[l], ew1, eb1, h1, BSZ, 256, 512, 1, stream);
        gemm<1>(h1, ew2, eb2, h2, BSZ, 256, 256, 1, stream);
        gemm<1>(h2, ew3, eb3, z_e, BSZ, 64, 256, 0, stream);

        // quantize
        float* zq = (l & 1) ? zq1 : zq0;
        hipLaunchKernelGGL(cb_norms, dim3((CB + 255) / 256), dim3(256), 0, stream, cb, cbn, CB);
        hipLaunchKernelGGL(vq_mfma, dim3(BSZ / 64), dim3(256), 0, stream, z_e, cb, cbn, zq, CB);

        // attention (l > 0): att = (zq_prev @ wv^T + bv) @ ow^T + ob  (loss-only)
        const float* attp = nullptr;
        if (l > 0) {
            const int ab = 42 + 4 * (l - 1);
            const float* iw = (const float*)d_in[ab + 0];
            const float* ib = (const float*)d_in[ab + 1];
            const float* ow = (const float*)d_in[ab + 2];
            const float* ob = (const float*)d_in[ab + 3];
            gemm<0>(zq_prev, iw + 128 * 64, ib + 128, vv, BSZ, 64, 64, 0, stream);
            gemm<0>(vv, ow, ob, att, BSZ, 64, 64, 0, stream);
            attp = att;
        }

        // losses (all fp32 operands)
        hipLaunchKernelGGL(loss_kernel, dim3(512), dim3(256), 0, stream,
                           z_e, zq, attp, vq_loss, commit,
                           BSZ * 64, 1.0f / (float)(BSZ * 64));

        // decoder (plain bf16: recon tolerance is fat)
        gemm<0>(zq, dw1, db1, h1, BSZ, 256, 64, 1, stream);
        gemm<0>(h1, dw2, db2, h2, BSZ, 256, 256, 1, stream);
        gemm<0>(h2, dw3, db3, out + (size_t)l * BSZ * 512, BSZ, 512, 256, 0, stream);

        zq_prev = zq;
    }
}

// Round 3
// 776.227 us; speedup vs baseline: 2.0172x; 1.2023x over previous
//
#include <hip/hip_runtime.h>

#define BSZ 16384

typedef __attribute__((ext_vector_type(8))) short bf16x8;
typedef __attribute__((ext_vector_type(4))) float f32x4;

__device__ inline unsigned short f2bf(float x) {
    unsigned u = __float_as_uint(x);
    u += 0x7fffu + ((u >> 16) & 1u);
    return (unsigned short)(u >> 16);
}
__device__ inline float bf2f(unsigned short h) {
    return __uint_as_float(((unsigned)h) << 16);
}
// pack fp32 -> interleaved (hi bf16 | lo bf16 << 16); hi+lo ~= x within 2^-16 rel
__device__ inline unsigned packbf(float v) {
    unsigned u = __float_as_uint(v);
    unsigned r = u + (0x7fffu + ((u >> 16) & 1u));
    unsigned hi = r >> 16;
    float rem = v - __uint_as_float(r & 0xffff0000u);
    unsigned lu = __float_as_uint(rem);
    unsigned lo = (lu + (0x7fffu + ((lu >> 16) & 1u))) >> 16;
    return hi | (lo << 16);
}
// reconstruct fp32 from interleaved pack
__device__ inline float unpackf(unsigned u) {
    return __uint_as_float(u << 16) + __uint_as_float(u & 0xffff0000u);
}
// 8 interleaved elems (two uint4) -> hi-plane and lo-plane bf16x8 frags
__device__ inline void unpack8(const uint4 p0, const uint4 p1, bf16x8& hi, bf16x8& lo) {
    union { unsigned u[4]; bf16x8 v; } H, L;
    H.u[0] = __builtin_amdgcn_perm(p0.y, p0.x, 0x05040100u);
    H.u[1] = __builtin_amdgcn_perm(p0.w, p0.z, 0x05040100u);
    H.u[2] = __builtin_amdgcn_perm(p1.y, p1.x, 0x05040100u);
    H.u[3] = __builtin_amdgcn_perm(p1.w, p1.z, 0x05040100u);
    L.u[0] = __builtin_amdgcn_perm(p0.y, p0.x, 0x07060302u);
    L.u[1] = __builtin_amdgcn_perm(p0.w, p0.z, 0x07060302u);
    L.u[2] = __builtin_amdgcn_perm(p1.y, p1.x, 0x07060302u);
    L.u[3] = __builtin_amdgcn_perm(p1.w, p1.z, 0x07060302u);
    hi = H.v; lo = L.v;
}

// ---------------- prep: fp32 -> interleaved planes, many tensors ----------------
struct PrepArgs {
    const float* src[28];
    unsigned* dst[28];
    int start[28];   // prefix (elements); all sizes multiples of 1024
    int nseg;
};
__global__ __launch_bounds__(256) void prep_kernel(PrepArgs pa) {
    const int base = blockIdx.x << 10;
    int seg = 0;
    #pragma unroll 1
    for (int i = 0; i < 27; ++i)
        if (seg + 1 < pa.nseg && base >= pa.start[seg + 1]) seg++;
    const int off = base - pa.start[seg] + (threadIdx.x << 2);
    const float4 v = *(const float4*)(pa.src[seg] + off);
    uint4 u;
    u.x = packbf(v.x); u.y = packbf(v.y); u.z = packbf(v.z); u.w = packbf(v.w);
    *(uint4*)(pa.dst[seg] + off) = u;
}

// ---------------- codebook norms (all 3 levels, fp32 inputs) ----------------
__global__ __launch_bounds__(256) void cb_norms3(
    const float* __restrict__ c0, const float* __restrict__ c1,
    const float* __restrict__ c2, float* __restrict__ cbn)
{
    const int r = blockIdx.x * 256 + threadIdx.x;   // 0..10239
    const float* src; int off;
    if (r < 2048) { src = c0; off = r; }
    else if (r < 6144) { src = c1; off = r - 2048; }
    else { src = c2; off = r - 6144; }
    const float4* p = (const float4*)(src + (size_t)off * 64);
    float s = 0.f;
    #pragma unroll
    for (int c = 0; c < 16; ++c) {
        float4 v = p[c];
        s += v.x * v.x + v.y * v.y + v.z * v.z + v.w * v.w;
    }
    cbn[r] = s;
}

// ---------------- MFMA GEMM on interleaved planes ----------------
// C = act(A @ W^T + bias). A: (M,K), W planes: (N,K), C: (M,N).
// SPLIT: 3-term split-bf16 (fp32-grade). A_F32: A is fp32, convert in staging.
// OUTP: write interleaved planes, else fp32. BM=128, BK=32, BN in {64,128}.
template<int SPLIT, int BN, int A_F32, int OUTP>
__global__ __launch_bounds__(256) void gemm3(
    const void* __restrict__ Ap_, const unsigned* __restrict__ Wp,
    const float* __restrict__ bias, void* __restrict__ Cp,
    int M, int N, int K, int relu)
{
    constexpr int NT = BN / 32;        // frags per wave in n
    __shared__ unsigned lds[128 * 36 + BN * 36];
    unsigned* Asm = lds;
    unsigned* Bsm = lds + 128 * 36;
    const int tid = threadIdx.x;
    const int m0 = blockIdx.y << 7;
    const int n0 = blockIdx.x * BN;
    const int lane = tid & 63, wv = tid >> 6;
    const int wm = wv >> 1, wn = wv & 1;
    const int q = lane >> 4, c16 = lane & 15;

    f32x4 acc[4][NT] = {};

    for (int k0 = 0; k0 < K; k0 += 32) {
        __syncthreads();
        // stage A (128 x 32 elems)
        #pragma unroll
        for (int i = 0; i < 4; ++i) {
            const int c = tid + (i << 8);
            const int row = c >> 3, col = (c & 7) << 2;
            uint4 u;
            if (A_F32) {
                const float4 v = *(const float4*)((const float*)Ap_ + (size_t)(m0 + row) * K + k0 + col);
                u.x = packbf(v.x); u.y = packbf(v.y); u.z = packbf(v.z); u.w = packbf(v.w);
            } else {
                u = *(const uint4*)((const unsigned*)Ap_ + (size_t)(m0 + row) * K + k0 + col);
            }
            *(uint4*)&Asm[row * 36 + col] = u;
        }
        // stage W (BN x 32)
        #pragma unroll
        for (int i = 0; i < BN / 32; ++i) {
            const int c = tid + (i << 8);
            const int row = c >> 3, col = (c & 7) << 2;
            const uint4 u = *(const uint4*)(Wp + (size_t)(n0 + row) * K + k0 + col);
            *(uint4*)&Bsm[row * 36 + col] = u;
        }
        __syncthreads();

        bf16x8 ah[4], al[4], bh[NT], bl[NT];
        #pragma unroll
        for (int mt = 0; mt < 4; ++mt) {
            const int r = wm * 64 + mt * 16 + c16;
            const int b = r * 36 + q * 8;
            unpack8(*(const uint4*)&Asm[b], *(const uint4*)&Asm[b + 4], ah[mt], al[mt]);
        }
        #pragma unroll
        for (int nt = 0; nt < NT; ++nt) {
            const int r = wn * (BN / 2) + nt * 16 + c16;
            const int b = r * 36 + q * 8;
            unpack8(*(const uint4*)&Bsm[b], *(const uint4*)&Bsm[b + 4], bh[nt], bl[nt]);
        }
        #pragma unroll
        for (int nt = 0; nt < NT; ++nt)
            #pragma unroll
            for (int mt = 0; mt < 4; ++mt) {
                acc[mt][nt] = __builtin_amdgcn_mfma_f32_16x16x32_bf16(ah[mt], bh[nt], acc[mt][nt], 0, 0, 0);
                if (SPLIT) {
                    acc[mt][nt] = __builtin_amdgcn_mfma_f32_16x16x32_bf16(ah[mt], bl[nt], acc[mt][nt], 0, 0, 0);
                    acc[mt][nt] = __builtin_amdgcn_mfma_f32_16x16x32_bf16(al[mt], bh[nt], acc[mt][nt], 0, 0, 0);
                }
            }
    }

    // epilogue: C/D layout col=lane&15, row=(lane>>4)*4+reg
    #pragma unroll
    for (int nt = 0; nt < NT; ++nt) {
        const int gcol = n0 + wn * (BN / 2) + nt * 16 + c16;
        const float bb = bias[gcol];
        #pragma unroll
        for (int mt = 0; mt < 4; ++mt)
            #pragma unroll
            for (int r = 0; r < 4; ++r) {
                const int grow = m0 + wm * 64 + mt * 16 + q * 4 + r;
                float v = acc[mt][nt][r] + bb;
                if (relu) v = fmaxf(v, 0.f);
                if (OUTP) ((unsigned*)Cp)[(size_t)grow * N + gcol] = packbf(v);
                else      ((float*)Cp)[(size_t)grow * N + gcol] = v;
            }
    }
}

// ---------------- VQ sweep: registers-only split-bf16 distance argmin ----------------
// grid = 512: block (g, half); 64 samples, half the codebook. No LDS in the loop;
// cb frags stream from L2 with one-tile prefetch. dist = |cb|^2 - 2 z.cb.
__global__ __launch_bounds__(256) void vq_sweep(
    const unsigned* __restrict__ zep, const unsigned* __restrict__ cbp,
    const float* __restrict__ cbn, float* __restrict__ bdo, int* __restrict__ bio,
    int half_sz)
{
    __shared__ float bd_s[64][4];
    __shared__ int   bi_s[64][4];
    const int tid = threadIdx.x;
    const int lane = tid & 63, wv = tid >> 6;
    const int q = lane >> 4, c16 = lane & 15;
    const int g = blockIdx.x >> 1, half = blockIdx.x & 1;
    const size_t s0 = (size_t)g << 6;
    const int e_base = half * half_sz;
    const int ntiles = half_sz >> 4;

    // A frags (z) in registers for the whole sweep
    bf16x8 ah[4][2], al[4][2];
    #pragma unroll
    for (int mt = 0; mt < 4; ++mt)
        #pragma unroll
        for (int ks = 0; ks < 2; ++ks) {
            const size_t a = (s0 + mt * 16 + c16) * 64 + ks * 32 + q * 8;
            unpack8(*(const uint4*)(zep + a), *(const uint4*)(zep + a + 4), ah[mt][ks], al[mt][ks]);
        }

    float bd[4][4];
    int   bi[4][4];
    #pragma unroll
    for (int mt = 0; mt < 4; ++mt)
        #pragma unroll
        for (int r = 0; r < 4; ++r) { bd[mt][r] = 3.4e38f; bi[mt][r] = 0x7fffffff; }

    uint4 cur[2][2]; float nn_c;
    auto ldB = [&](int t, uint4 pb[2][2], float& nn) {
        const int e0 = e_base + t * 16;
        #pragma unroll
        for (int ks = 0; ks < 2; ++ks) {
            const size_t a = (size_t)(e0 + c16) * 64 + ks * 32 + q * 8;
            pb[ks][0] = *(const uint4*)(cbp + a);
            pb[ks][1] = *(const uint4*)(cbp + a + 4);
        }
        nn = cbn[e0 + c16];
    };
    ldB(wv, cur, nn_c);

    for (int t = wv; t < ntiles; t += 4) {
        const int tn = (t + 4 < ntiles) ? t + 4 : t;
        uint4 nxt[2][2]; float nn_n;
        ldB(tn, nxt, nn_n);

        bf16x8 bh[2], bl[2];
        #pragma unroll
        for (int ks = 0; ks < 2; ++ks) unpack8(cur[ks][0], cur[ks][1], bh[ks], bl[ks]);

        f32x4 acc[4] = {};
        #pragma unroll
        for (int ks = 0; ks < 2; ++ks)
            #pragma unroll
            for (int mt = 0; mt < 4; ++mt) {
                acc[mt] = __builtin_amdgcn_mfma_f32_16x16x32_bf16(ah[mt][ks], bh[ks], acc[mt], 0, 0, 0);
                acc[mt] = __builtin_amdgcn_mfma_f32_16x16x32_bf16(ah[mt][ks], bl[ks], acc[mt], 0, 0, 0);
                acc[mt] = __builtin_amdgcn_mfma_f32_16x16x32_bf16(al[mt][ks], bh[ks], acc[mt], 0, 0, 0);
            }

        const int eidx = e_base + t * 16 + c16;
        #pragma unroll
        for (int mt = 0; mt < 4; ++mt)
            #pragma unroll
            for (int r = 0; r < 4; ++r) {
                const float dist = nn_c - 2.0f * acc[mt][r];
                if (dist < bd[mt][r]) { bd[mt][r] = dist; bi[mt][r] = eidx; }
            }
        #pragma unroll
        for (int ks = 0; ks < 2; ++ks) { cur[ks][0] = nxt[ks][0]; cur[ks][1] = nxt[ks][1]; }
        nn_c = nn_n;
    }

    // reduce over 16 entry-lanes (xor < 16 stays within sample row group)
    #pragma unroll
    for (int off = 1; off < 16; off <<= 1)
        #pragma unroll
        for (int mt = 0; mt < 4; ++mt)
            #pragma unroll
            for (int r = 0; r < 4; ++r) {
                const float od = __shfl_xor(bd[mt][r], off, 64);
                const int   oi = __shfl_xor(bi[mt][r], off, 64);
                if (od < bd[mt][r] || (od == bd[mt][r] && oi < bi[mt][r])) {
                    bd[mt][r] = od; bi[mt][r] = oi;
                }
            }
    if (c16 == 0)
        #pragma unroll
        for (int mt = 0; mt < 4; ++mt)
            #pragma unroll
            for (int r = 0; r < 4; ++r) {
                const int row = mt * 16 + q * 4 + r;
                bd_s[row][wv] = bd[mt][r];
                bi_s[row][wv] = bi[mt][r];
            }
    __syncthreads();
    if (tid < 64) {
        float best = bd_s[tid][0];
        int   bidx = bi_s[tid][0];
        #pragma unroll
        for (int w2 = 1; w2 < 4; ++w2) {
            const float d = bd_s[tid][w2];
            const int   i2 = bi_s[tid][w2];
            if (d < best || (d == best && i2 < bidx)) { best = d; bidx = i2; }
        }
        bdo[half * BSZ + s0 + tid] = best;
        bio[half * BSZ + s0 + tid] = bidx;
    }
}

// ---------------- merge halves + gather zq planes ----------------
__global__ __launch_bounds__(256) void merge_gather(
    const float* __restrict__ bd, const int* __restrict__ bi,
    const unsigned* __restrict__ cbp, unsigned* __restrict__ zqp)
{
    const int gid = blockIdx.x * 256 + threadIdx.x;
    const int s = gid >> 6, d = gid & 63;
    const float d0 = bd[s], d1 = bd[BSZ + s];
    const int   i0 = bi[s], i1 = bi[BSZ + s];
    const int idx = (d1 < d0) ? i1 : i0;   // tie -> i0 (lower index, half 0)
    zqp[gid] = cbp[(size_t)idx * 64 + d];
}

// ---------------- losses ----------------
__global__ __launch_bounds__(256) void loss3(
    const unsigned* __restrict__ zep, const unsigned* __restrict__ zqp,
    const float* __restrict__ att, float* __restrict__ vq_out,
    float* __restrict__ commit_out, int n, float inv)
{
    float cs = 0.f, vs = 0.f;
    for (int t = blockIdx.x * 256 + threadIdx.x; t < n; t += gridDim.x * 256) {
        const float e = unpackf(zep[t]);
        const float qv = unpackf(zqp[t]);
        const float dc = e - qv;
        cs += dc * dc;
        const float za = att ? (e + att[t]) : e;
        const float dv = qv - za;
        vs += dv * dv;
    }
    #pragma unroll
    for (int off = 32; off; off >>= 1) {
        cs += __shfl_down(cs, off, 64);
        vs += __shfl_down(vs, off, 64);
    }
    __shared__ float sc[4], sv[4];
    const int lane = threadIdx.x & 63, w = threadIdx.x >> 6;
    if (lane == 0) { sc[w] = cs; sv[w] = vs; }
    __syncthreads();
    if (threadIdx.x == 0) {
        atomicAdd(commit_out, (sc[0] + sc[1] + sc[2] + sc[3]) * inv);
        atomicAdd(vq_out, (sv[0] + sv[1] + sv[2] + sv[3]) * inv);
    }
}

template<int SPLIT, int BN, int A_F32, int OUTP>
static inline void gemm(const void* A, const unsigned* W, const float* b, void* C,
                        int M, int N, int K, int relu, hipStream_t s)
{
    dim3 g(N / BN, M >> 7);
    hipLaunchKernelGGL((gemm3<SPLIT, BN, A_F32, OUTP>), g, dim3(256), 0, s, A, W, b, C, M, N, K, relu);
}

extern "C" void kernel_launch(void* const* d_in, const int* in_sizes, int n_in,
                              void* d_out, int out_size, void* d_ws, size_t ws_size,
                              hipStream_t stream)
{
    const int CB_SIZES[3] = {2048, 4096, 4096};
    const float* x[3] = {(const float*)d_in[0], (const float*)d_in[1], (const float*)d_in[2]};

    // ---- workspace layout (54.24 MB, all uint/float 4B units) ----
    unsigned* P1  = (unsigned*)d_ws;                 // 16384*256 (h1 / vv planes)
    unsigned* P2  = P1 + (size_t)BSZ * 256;          // 16384*256 (h2 planes / att f32)
    unsigned* zep = P2 + (size_t)BSZ * 256;          // 16384*64
    unsigned* zq0 = zep + (size_t)BSZ * 64;
    unsigned* zq1 = zq0 + (size_t)BSZ * 64;
    float* cbn    = (float*)(zq1 + (size_t)BSZ * 64);  // 10240
    float* bd     = cbn + 10240;                      // 2*16384
    int*   bi     = (int*)(bd + 2 * BSZ);             // 2*16384
    unsigned* wp  = (unsigned*)(bi + 2 * BSZ);        // weight/cb planes

    float* out = (float*)d_out;
    float* vq_loss = out + (size_t)3 * BSZ * 512;
    float* commit  = vq_loss + 1;
    hipMemsetAsync(vq_loss, 0, 2 * sizeof(float), stream);

    // ---- prep descriptor table ----
    PrepArgs pa; int pos = 0, ns = 0;
    const unsigned* ew1p[3]; const unsigned* ew2p[3]; const unsigned* ew3p[3];
    const unsigned* dw1p[3]; const unsigned* dw2p[3]; const unsigned* dw3p[3];
    const unsigned* cbp[3];  const unsigned* awvp[2]; const unsigned* aowp[2];
    auto add = [&](const float* src, int n) -> const unsigned* {
        pa.src[ns] = src; pa.dst[ns] = wp + pos; pa.start[ns] = pos;
        pos += n; ns++; return wp + pos - n;
    };
    for (int l = 0; l < 3; ++l) {
        const int base = 3 + 13 * l;
        ew1p[l] = add((const float*)d_in[base + 0], 256 * 512);
        ew2p[l] = add((const float*)d_in[base + 2], 256 * 256);
        ew3p[l] = add((const float*)d_in[base + 4], 64 * 256);
        dw1p[l] = add((const float*)d_in[base + 6], 256 * 64);
        dw2p[l] = add((const float*)d_in[base + 8], 256 * 256);
        dw3p[l] = add((const float*)d_in[base + 10], 512 * 256);
        cbp[l]  = add((const float*)d_in[base + 12], CB_SIZES[l] * 64);
    }
    for (int j = 0; j < 2; ++j) {
        awvp[j] = add((const float*)d_in[42 + 4 * j] + 128 * 64, 64 * 64);
        aowp[j] = add((const float*)d_in[42 + 4 * j + 2], 64 * 64);
    }
    pa.start[ns] = pos; pa.nseg = ns;
    for (int i = ns + 1; i < 28; ++i) pa.start[i] = 0x7fffffff;

    hipLaunchKernelGGL(prep_kernel, dim3(pos >> 10), dim3(256), 0, stream, pa);
    hipLaunchKernelGGL(cb_norms3, dim3(40), dim3(256), 0, stream,
                       (const float*)d_in[15], (const float*)d_in[28], (const float*)d_in[41], cbn);

    const unsigned* zq_prev = nullptr;
    for (int l = 0; l < 3; ++l) {
        const int base = 3 + 13 * l;
        const float* eb1 = (const float*)d_in[base + 1];
        const float* eb2 = (const float*)d_in[base + 3];
        const float* eb3 = (const float*)d_in[base + 5];
        const float* db1 = (const float*)d_in[base + 7];
        const float* db2 = (const float*)d_in[base + 9];
        const float* db3 = (const float*)d_in[base + 11];
        const int CB = CB_SIZES[l];
        const float* cbn_l = cbn + (l == 0 ? 0 : (l == 1 ? 2048 : 6144));

        // encoder: split-bf16 (fp32-grade) -> z_e planes
        gemm<1, 128, 1, 1>(x[l], ew1p[l], eb1, P1, BSZ, 256, 512, 1, stream);
        gemm<1, 128, 0, 1>(P1, ew2p[l], eb2, P2, BSZ, 256, 256, 1, stream);
        gemm<1, 64, 0, 1>(P2, ew3p[l], eb3, zep, BSZ, 64, 256, 0, stream);

        // quantize: sweep halves + merge/gather
        unsigned* zq = (l & 1) ? zq1 : zq0;
        hipLaunchKernelGGL(vq_sweep, dim3(512), dim3(256), 0, stream,
                           zep, cbp[l], cbn_l, bd, bi, CB / 2);
        hipLaunchKernelGGL(merge_gather, dim3(BSZ * 64 / 256), dim3(256), 0, stream,
                           bd, bi, cbp[l], zq);

        // attention (loss-only): zq_prev -> vv (P1 planes) -> att (P2 as fp32)
        const float* attp = nullptr;
        if (l > 0) {
            const float* ib = (const float*)d_in[42 + 4 * (l - 1) + 1];
            const float* ob = (const float*)d_in[42 + 4 * (l - 1) + 3];
            gemm<0, 64, 0, 1>(zq_prev, awvp[l - 1], ib + 128, P1, BSZ, 64, 64, 0, stream);
            gemm<0, 64, 0, 0>(P1, aowp[l - 1], ob, P2, BSZ, 64, 64, 0, stream);
            attp = (const float*)P2;
        }

        hipLaunchKernelGGL(loss3, dim3(512), dim3(256), 0, stream,
                           zep, zq, attp, vq_loss, commit, BSZ * 64, 1.0f / (float)(BSZ * 64));

        // decoder: plain bf16 (hi planes only)
        gemm<0, 128, 0, 1>(zq, dw1p[l], db1, P1, BSZ, 256, 64, 1, stream);
        gemm<0, 128, 0, 1>(P1, dw2p[l], db2, P2, BSZ, 256, 256, 1, stream);
        gemm<0, 128, 0, 0>(P2, dw3p[l], db3, out + (size_t)l * BSZ * 512, BSZ, 512, 256, 0, stream);

        zq_prev = zq;
    }
}

// Round 4
// 644.708 us; speedup vs baseline: 2.4287x; 1.2040x over previous
//
#include <hip/hip_runtime.h>

#define BSZ 16384

typedef __attribute__((ext_vector_type(8))) short bf16x8;
typedef __attribute__((ext_vector_type(4))) float f32x4;

// pack fp32 -> interleaved (hi bf16 | lo bf16 << 16); hi+lo ~= x within 2^-16 rel
__device__ inline unsigned packbf(float v) {
    unsigned u = __float_as_uint(v);
    unsigned r = u + (0x7fffu + ((u >> 16) & 1u));
    unsigned hi = r >> 16;
    float rem = v - __uint_as_float(r & 0xffff0000u);
    unsigned lu = __float_as_uint(rem);
    unsigned lo = (lu + (0x7fffu + ((lu >> 16) & 1u))) >> 16;
    return hi | (lo << 16);
}
__device__ inline float unpackf(unsigned u) {
    return __uint_as_float(u << 16) + __uint_as_float(u & 0xffff0000u);
}
// 8 interleaved elems (two uint4) -> hi-plane and lo-plane bf16x8 frags
__device__ inline void unpack8(const uint4 p0, const uint4 p1, bf16x8& hi, bf16x8& lo) {
    union { unsigned u[4]; bf16x8 v; } H, L;
    H.u[0] = __builtin_amdgcn_perm(p0.y, p0.x, 0x05040100u);
    H.u[1] = __builtin_amdgcn_perm(p0.w, p0.z, 0x05040100u);
    H.u[2] = __builtin_amdgcn_perm(p1.y, p1.x, 0x05040100u);
    H.u[3] = __builtin_amdgcn_perm(p1.w, p1.z, 0x05040100u);
    L.u[0] = __builtin_amdgcn_perm(p0.y, p0.x, 0x07060302u);
    L.u[1] = __builtin_amdgcn_perm(p0.w, p0.z, 0x07060302u);
    L.u[2] = __builtin_amdgcn_perm(p1.y, p1.x, 0x07060302u);
    L.u[3] = __builtin_amdgcn_perm(p1.w, p1.z, 0x07060302u);
    hi = H.v; lo = L.v;
}

// ---------------- prep: fp32 -> interleaved planes, many tensors ----------------
struct PrepArgs {
    const float* src[24];
    unsigned* dst[24];
    int start[24];   // prefix (elements); all sizes multiples of 1024
    int nseg;
};
__global__ __launch_bounds__(256) void prep_kernel(PrepArgs pa) {
    const int base = blockIdx.x << 10;
    int seg = 0;
    #pragma unroll 1
    for (int i = 0; i < 23; ++i)
        if (seg + 1 < pa.nseg && base >= pa.start[seg + 1]) seg++;
    const int off = base - pa.start[seg] + (threadIdx.x << 2);
    const float4 v = *(const float4*)(pa.src[seg] + off);
    uint4 u;
    u.x = packbf(v.x); u.y = packbf(v.y); u.z = packbf(v.z); u.w = packbf(v.w);
    *(uint4*)(pa.dst[seg] + off) = u;
}

// ---------------- codebook norms (all 3 levels, fp32 inputs) ----------------
__global__ __launch_bounds__(256) void cb_norms3(
    const float* __restrict__ c0, const float* __restrict__ c1,
    const float* __restrict__ c2, float* __restrict__ cbn)
{
    const int r = blockIdx.x * 256 + threadIdx.x;   // 0..10239
    const float* src; int off;
    if (r < 2048) { src = c0; off = r; }
    else if (r < 6144) { src = c1; off = r - 2048; }
    else { src = c2; off = r - 6144; }
    const float4* p = (const float4*)(src + (size_t)off * 64);
    float s = 0.f;
    #pragma unroll
    for (int c = 0; c < 16; ++c) {
        float4 v = p[c];
        s += v.x * v.x + v.y * v.y + v.z * v.z + v.w * v.w;
    }
    cbn[r] = s;
}

// ---------------- attention fold: W_comb = ow@wv (planes), b_comb = ow@bv + ob ----
__global__ __launch_bounds__(256) void attn_combine(
    const float* __restrict__ iw, const float* __restrict__ ib,
    const float* __restrict__ ow, const float* __restrict__ ob,
    unsigned* __restrict__ wcomb, float* __restrict__ bcomb)
{
    __shared__ float o[4096], v[4096];
    const float* wv = iw + 128 * 64;
    for (int t = threadIdx.x; t < 4096; t += 256) { o[t] = ow[t]; v[t] = wv[t]; }
    __syncthreads();
    for (int t = threadIdx.x; t < 4096; t += 256) {
        const int j = t >> 6, i = t & 63;
        float s = 0.f;
        #pragma unroll
        for (int k = 0; k < 64; ++k) s += o[j * 64 + k] * v[k * 64 + i];
        wcomb[t] = packbf(s);
    }
    if (threadIdx.x < 64) {
        const int j = threadIdx.x;
        const float* bv = ib + 128;
        float s = ob[j];
        #pragma unroll
        for (int k = 0; k < 64; ++k) s += o[j * 64 + k] * bv[k];
        bcomb[j] = s;
    }
}

// ---------------- batched MFMA GEMM on interleaved planes ----------------
// Per z-slice: C = act(A @ W^T + bias). BM=128, BK=32.
struct GemmB {
    const void* A[3];
    const unsigned* W[3];
    const float* bias[3];
    void* C[3];
};
template<int SPLIT, int BN, int A_F32, int OUTP>
__global__ __launch_bounds__(256) void gemmb(
    GemmB g, int M, int N, int K, int relu)
{
    constexpr int NT = BN / 32;
    __shared__ unsigned lds[128 * 36 + BN * 36];
    unsigned* Asm = lds;
    unsigned* Bsm = lds + 128 * 36;
    const int z = blockIdx.z;
    const void* Ap_ = g.A[z];
    const unsigned* Wp = g.W[z];
    const float* bias = g.bias[z];
    void* Cp = g.C[z];
    const int tid = threadIdx.x;
    const int m0 = blockIdx.y << 7;
    const int n0 = blockIdx.x * BN;
    const int lane = tid & 63, wv = tid >> 6;
    const int wm = wv >> 1, wn = wv & 1;
    const int q = lane >> 4, c16 = lane & 15;

    f32x4 acc[4][NT] = {};

    for (int k0 = 0; k0 < K; k0 += 32) {
        __syncthreads();
        #pragma unroll
        for (int i = 0; i < 4; ++i) {
            const int c = tid + (i << 8);
            const int row = c >> 3, col = (c & 7) << 2;
            uint4 u;
            if (A_F32) {
                const float4 v = *(const float4*)((const float*)Ap_ + (size_t)(m0 + row) * K + k0 + col);
                u.x = packbf(v.x); u.y = packbf(v.y); u.z = packbf(v.z); u.w = packbf(v.w);
            } else {
                u = *(const uint4*)((const unsigned*)Ap_ + (size_t)(m0 + row) * K + k0 + col);
            }
            *(uint4*)&Asm[row * 36 + col] = u;
        }
        #pragma unroll
        for (int i = 0; i < BN / 32; ++i) {
            const int c = tid + (i << 8);
            const int row = c >> 3, col = (c & 7) << 2;
            const uint4 u = *(const uint4*)(Wp + (size_t)(n0 + row) * K + k0 + col);
            *(uint4*)&Bsm[row * 36 + col] = u;
        }
        __syncthreads();

        bf16x8 ah[4], al[4], bh[NT], bl[NT];
        #pragma unroll
        for (int mt = 0; mt < 4; ++mt) {
            const int r = wm * 64 + mt * 16 + c16;
            const int b = r * 36 + q * 8;
            unpack8(*(const uint4*)&Asm[b], *(const uint4*)&Asm[b + 4], ah[mt], al[mt]);
        }
        #pragma unroll
        for (int nt = 0; nt < NT; ++nt) {
            const int r = wn * (BN / 2) + nt * 16 + c16;
            const int b = r * 36 + q * 8;
            unpack8(*(const uint4*)&Bsm[b], *(const uint4*)&Bsm[b + 4], bh[nt], bl[nt]);
        }
        #pragma unroll
        for (int nt = 0; nt < NT; ++nt)
            #pragma unroll
            for (int mt = 0; mt < 4; ++mt) {
                acc[mt][nt] = __builtin_amdgcn_mfma_f32_16x16x32_bf16(ah[mt], bh[nt], acc[mt][nt], 0, 0, 0);
                if (SPLIT) {
                    acc[mt][nt] = __builtin_amdgcn_mfma_f32_16x16x32_bf16(ah[mt], bl[nt], acc[mt][nt], 0, 0, 0);
                    acc[mt][nt] = __builtin_amdgcn_mfma_f32_16x16x32_bf16(al[mt], bh[nt], acc[mt][nt], 0, 0, 0);
                }
            }
    }

    #pragma unroll
    for (int nt = 0; nt < NT; ++nt) {
        const int gcol = n0 + wn * (BN / 2) + nt * 16 + c16;
        const float bb = bias[gcol];
        #pragma unroll
        for (int mt = 0; mt < 4; ++mt)
            #pragma unroll
            for (int r = 0; r < 4; ++r) {
                const int grow = m0 + wm * 64 + mt * 16 + q * 4 + r;
                float v = acc[mt][nt][r] + bb;
                if (relu) v = fmaxf(v, 0.f);
                if (OUTP) ((unsigned*)Cp)[(size_t)grow * N + gcol] = packbf(v);
                else      ((float*)Cp)[(size_t)grow * N + gcol] = v;
            }
    }
}

// ---------------- VQ sweep: 10 equal 1024-entry chunks across 3 codebooks ----------
struct VqB {
    const unsigned* zep[10];
    const unsigned* cbp[10];
    const float* cbn[10];
    int e_base[10];
};
__global__ __launch_bounds__(256) void vq_sweep(
    VqB vb, float* __restrict__ bdo, int* __restrict__ bio)
{
    __shared__ float bd_s[64][4];
    __shared__ int   bi_s[64][4];
    const int tid = threadIdx.x;
    const int lane = tid & 63, wv = tid >> 6;
    const int q = lane >> 4, c16 = lane & 15;
    const int chunk = blockIdx.y;
    const size_t s0 = (size_t)blockIdx.x << 6;
    const unsigned* zep = vb.zep[chunk];
    const unsigned* cbp = vb.cbp[chunk];
    const float* cbn = vb.cbn[chunk];
    const int e_base = vb.e_base[chunk];
    const int ntiles = 64;   // 1024 entries / 16

    bf16x8 ah[4][2], al[4][2];
    #pragma unroll
    for (int mt = 0; mt < 4; ++mt)
        #pragma unroll
        for (int ks = 0; ks < 2; ++ks) {
            const size_t a = (s0 + mt * 16 + c16) * 64 + ks * 32 + q * 8;
            unpack8(*(const uint4*)(zep + a), *(const uint4*)(zep + a + 4), ah[mt][ks], al[mt][ks]);
        }

    float bd[4][4];
    int   bi[4][4];
    #pragma unroll
    for (int mt = 0; mt < 4; ++mt)
        #pragma unroll
        for (int r = 0; r < 4; ++r) { bd[mt][r] = 3.4e38f; bi[mt][r] = 0x7fffffff; }

    uint4 cur[2][2]; float nn_c;
    auto ldB = [&](int t, uint4 pb[2][2], float& nn) {
        const int e0 = e_base + t * 16;
        #pragma unroll
        for (int ks = 0; ks < 2; ++ks) {
            const size_t a = (size_t)(e0 + c16) * 64 + ks * 32 + q * 8;
            pb[ks][0] = *(const uint4*)(cbp + a);
            pb[ks][1] = *(const uint4*)(cbp + a + 4);
        }
        nn = cbn[e0 + c16];
    };
    ldB(wv, cur, nn_c);

    for (int t = wv; t < ntiles; t += 4) {
        const int tn = (t + 4 < ntiles) ? t + 4 : t;
        uint4 nxt[2][2]; float nn_n;
        ldB(tn, nxt, nn_n);

        bf16x8 bh[2], bl[2];
        #pragma unroll
        for (int ks = 0; ks < 2; ++ks) unpack8(cur[ks][0], cur[ks][1], bh[ks], bl[ks]);

        f32x4 acc[4] = {};
        #pragma unroll
        for (int ks = 0; ks < 2; ++ks)
            #pragma unroll
            for (int mt = 0; mt < 4; ++mt) {
                acc[mt] = __builtin_amdgcn_mfma_f32_16x16x32_bf16(ah[mt][ks], bh[ks], acc[mt], 0, 0, 0);
                acc[mt] = __builtin_amdgcn_mfma_f32_16x16x32_bf16(ah[mt][ks], bl[ks], acc[mt], 0, 0, 0);
                acc[mt] = __builtin_amdgcn_mfma_f32_16x16x32_bf16(al[mt][ks], bh[ks], acc[mt], 0, 0, 0);
            }

        const int eidx = e_base + t * 16 + c16;
        #pragma unroll
        for (int mt = 0; mt < 4; ++mt)
            #pragma unroll
            for (int r = 0; r < 4; ++r) {
                const float dist = nn_c - 2.0f * acc[mt][r];
                if (dist < bd[mt][r]) { bd[mt][r] = dist; bi[mt][r] = eidx; }
            }
        #pragma unroll
        for (int ks = 0; ks < 2; ++ks) { cur[ks][0] = nxt[ks][0]; cur[ks][1] = nxt[ks][1]; }
        nn_c = nn_n;
    }

    #pragma unroll
    for (int off = 1; off < 16; off <<= 1)
        #pragma unroll
        for (int mt = 0; mt < 4; ++mt)
            #pragma unroll
            for (int r = 0; r < 4; ++r) {
                const float od = __shfl_xor(bd[mt][r], off, 64);
                const int   oi = __shfl_xor(bi[mt][r], off, 64);
                if (od < bd[mt][r] || (od == bd[mt][r] && oi < bi[mt][r])) {
                    bd[mt][r] = od; bi[mt][r] = oi;
                }
            }
    if (c16 == 0)
        #pragma unroll
        for (int mt = 0; mt < 4; ++mt)
            #pragma unroll
            for (int r = 0; r < 4; ++r) {
                const int row = mt * 16 + q * 4 + r;
                bd_s[row][wv] = bd[mt][r];
                bi_s[row][wv] = bi[mt][r];
            }
    __syncthreads();
    if (tid < 64) {
        float best = bd_s[tid][0];
        int   bidx = bi_s[tid][0];
        #pragma unroll
        for (int w2 = 1; w2 < 4; ++w2) {
            const float d = bd_s[tid][w2];
            const int   i2 = bi_s[tid][w2];
            if (d < best || (d == best && i2 < bidx)) { best = d; bidx = i2; }
        }
        bdo[(size_t)chunk * BSZ + s0 + tid] = best;
        bio[(size_t)chunk * BSZ + s0 + tid] = bidx;
    }
}

// ---------------- merge chunks + gather zq planes (all 3 levels) ----------------
__global__ __launch_bounds__(256) void merge_gather_b(
    const float* __restrict__ bd, const int* __restrict__ bi,
    const unsigned* __restrict__ cb0, const unsigned* __restrict__ cb1,
    const unsigned* __restrict__ cb2, unsigned* __restrict__ zq_all)
{
    const int gid = blockIdx.x * 256 + threadIdx.x;   // 0 .. 3*BSZ*64
    const int l = gid / (BSZ * 64);
    const int r = gid - l * (BSZ * 64);
    const int s = r >> 6, d = r & 63;
    const int c0 = (l == 0) ? 0 : (l == 1 ? 2 : 6);
    const int c1 = (l == 0) ? 2 : (l == 1 ? 6 : 10);
    float best = bd[(size_t)c0 * BSZ + s];
    int   idx  = bi[(size_t)c0 * BSZ + s];
    for (int c = c0 + 1; c < c1; ++c) {
        const float dd = bd[(size_t)c * BSZ + s];
        const int   ii = bi[(size_t)c * BSZ + s];
        if (dd < best || (dd == best && ii < idx)) { best = dd; idx = ii; }
    }
    const unsigned* cb = (l == 0) ? cb0 : (l == 1 ? cb1 : cb2);
    zq_all[gid] = cb[(size_t)idx * 64 + d];
}

// ---------------- batched losses ----------------
__global__ __launch_bounds__(256) void loss_b(
    const unsigned* __restrict__ zep0, const unsigned* __restrict__ zq0,
    const unsigned* __restrict__ attb, float* __restrict__ vq_out,
    float* __restrict__ commit_out, float inv)
{
    const int l = blockIdx.z;
    const unsigned* ze = zep0 + (size_t)l * BSZ * 64;
    const unsigned* zq = zq0 + (size_t)l * BSZ * 64;
    const unsigned* at = (l > 0) ? attb + (size_t)(l - 1) * BSZ * 64 : nullptr;
    float cs = 0.f, vs = 0.f;
    for (int t = blockIdx.x * 256 + threadIdx.x; t < BSZ * 64; t += gridDim.x * 256) {
        const float e = unpackf(ze[t]);
        const float qv = unpackf(zq[t]);
        const float dc = e - qv;
        cs += dc * dc;
        const float za = at ? (e + unpackf(at[t])) : e;
        const float dv = qv - za;
        vs += dv * dv;
    }
    #pragma unroll
    for (int off = 32; off; off >>= 1) {
        cs += __shfl_down(cs, off, 64);
        vs += __shfl_down(vs, off, 64);
    }
    __shared__ float sc[4], sv[4];
    const int lane = threadIdx.x & 63, w = threadIdx.x >> 6;
    if (lane == 0) { sc[w] = cs; sv[w] = vs; }
    __syncthreads();
    if (threadIdx.x == 0) {
        atomicAdd(commit_out, (sc[0] + sc[1] + sc[2] + sc[3]) * inv);
        atomicAdd(vq_out, (sv[0] + sv[1] + sv[2] + sv[3]) * inv);
    }
}

extern "C" void kernel_launch(void* const* d_in, const int* in_sizes, int n_in,
                              void* d_out, int out_size, void* d_ws, size_t ws_size,
                              hipStream_t stream)
{
    const int CB_SIZES[3] = {2048, 4096, 4096};

    // ---- workspace layout (u32 units; ~145 MB total) ----
    unsigned* H1   = (unsigned*)d_ws;                  // 3 * B*256
    unsigned* H2   = H1 + (size_t)3 * BSZ * 256;       // 3 * B*256
    unsigned* ZEP  = H2 + (size_t)3 * BSZ * 256;       // 3 * B*64
    unsigned* ZQ   = ZEP + (size_t)3 * BSZ * 64;       // 3 * B*64
    unsigned* ATT  = ZQ + (size_t)3 * BSZ * 64;        // 2 * B*64
    float* cbn     = (float*)(ATT + (size_t)2 * BSZ * 64);  // 10240
    float* bd      = cbn + 10240;                      // 10 * BSZ
    int*   bi      = (int*)(bd + 10 * BSZ);            // 10 * BSZ
    unsigned* wcb  = (unsigned*)(bi + 10 * BSZ);       // 2*4096 wcomb planes
    float* bcomb   = (float*)(wcb + 2 * 4096);         // 2*64
    unsigned* wp   = (unsigned*)(bcomb + 128);         // weight/cb planes

    float* out = (float*)d_out;
    float* vq_loss = out + (size_t)3 * BSZ * 512;
    float* commit  = vq_loss + 1;
    hipMemsetAsync(vq_loss, 0, 2 * sizeof(float), stream);

    // ---- prep descriptor table ----
    PrepArgs pa; int pos = 0, ns = 0;
    const unsigned* ew1p[3]; const unsigned* ew2p[3]; const unsigned* ew3p[3];
    const unsigned* dw1p[3]; const unsigned* dw2p[3]; const unsigned* dw3p[3];
    const unsigned* cbp[3];
    auto add = [&](const float* src, int n) -> const unsigned* {
        pa.src[ns] = src; pa.dst[ns] = wp + pos; pa.start[ns] = pos;
        pos += n; ns++; return wp + pos - n;
    };
    for (int l = 0; l < 3; ++l) {
        const int base = 3 + 13 * l;
        ew1p[l] = add((const float*)d_in[base + 0], 256 * 512);
        ew2p[l] = add((const float*)d_in[base + 2], 256 * 256);
        ew3p[l] = add((const float*)d_in[base + 4], 64 * 256);
        dw1p[l] = add((const float*)d_in[base + 6], 256 * 64);
        dw2p[l] = add((const float*)d_in[base + 8], 256 * 256);
        dw3p[l] = add((const float*)d_in[base + 10], 512 * 256);
        cbp[l]  = add((const float*)d_in[base + 12], CB_SIZES[l] * 64);
    }
    pa.start[ns] = pos; pa.nseg = ns;
    for (int i = ns + 1; i < 24; ++i) pa.start[i] = 0x7fffffff;

    hipLaunchKernelGGL(prep_kernel, dim3(pos >> 10), dim3(256), 0, stream, pa);
    hipLaunchKernelGGL(cb_norms3, dim3(40), dim3(256), 0, stream,
                       (const float*)d_in[15], (const float*)d_in[28], (const float*)d_in[41], cbn);
    for (int j = 0; j < 2; ++j)
        hipLaunchKernelGGL(attn_combine, dim3(1), dim3(256), 0, stream,
                           (const float*)d_in[42 + 4 * j], (const float*)d_in[42 + 4 * j + 1],
                           (const float*)d_in[42 + 4 * j + 2], (const float*)d_in[42 + 4 * j + 3],
                           wcb + j * 4096, bcomb + j * 64);

    // ---- encoders, batched over levels (split-bf16, fp32-grade) ----
    GemmB g;
    for (int l = 0; l < 3; ++l) {
        g.A[l] = d_in[l]; g.W[l] = ew1p[l];
        g.bias[l] = (const float*)d_in[3 + 13 * l + 1];
        g.C[l] = H1 + (size_t)l * BSZ * 256;
    }
    hipLaunchKernelGGL((gemmb<1, 128, 1, 1>), dim3(2, 128, 3), dim3(256), 0, stream,
                       g, BSZ, 256, 512, 1);
    for (int l = 0; l < 3; ++l) {
        g.A[l] = H1 + (size_t)l * BSZ * 256; g.W[l] = ew2p[l];
        g.bias[l] = (const float*)d_in[3 + 13 * l + 3];
        g.C[l] = H2 + (size_t)l * BSZ * 256;
    }
    hipLaunchKernelGGL((gemmb<1, 128, 0, 1>), dim3(2, 128, 3), dim3(256), 0, stream,
                       g, BSZ, 256, 256, 1);
    for (int l = 0; l < 3; ++l) {
        g.A[l] = H2 + (size_t)l * BSZ * 256; g.W[l] = ew3p[l];
        g.bias[l] = (const float*)d_in[3 + 13 * l + 5];
        g.C[l] = ZEP + (size_t)l * BSZ * 64;
    }
    hipLaunchKernelGGL((gemmb<1, 64, 0, 1>), dim3(1, 128, 3), dim3(256), 0, stream,
                       g, BSZ, 64, 256, 0);

    // ---- VQ: 10 chunks of 1024 entries (l0:2, l1:4, l2:4) ----
    VqB vb;
    {
        int c = 0;
        for (int l = 0; l < 3; ++l) {
            const int nch = CB_SIZES[l] / 1024;
            const int cb_off = (l == 0) ? 0 : (l == 1 ? 2048 : 6144);
            for (int k = 0; k < nch; ++k, ++c) {
                vb.zep[c] = ZEP + (size_t)l * BSZ * 64;
                vb.cbp[c] = cbp[l];
                vb.cbn[c] = cbn + cb_off;
                vb.e_base[c] = k * 1024;
            }
        }
    }
    hipLaunchKernelGGL(vq_sweep, dim3(BSZ / 64, 10), dim3(256), 0, stream, vb, bd, bi);
    hipLaunchKernelGGL(merge_gather_b, dim3(3 * BSZ * 64 / 256), dim3(256), 0, stream,
                       bd, bi, cbp[0], cbp[1], cbp[2], ZQ);

    // ---- folded attention (loss-only), batched over 2 ----
    for (int j = 0; j < 2; ++j) {
        g.A[j] = ZQ + (size_t)j * BSZ * 64;
        g.W[j] = wcb + j * 4096;
        g.bias[j] = bcomb + j * 64;
        g.C[j] = ATT + (size_t)j * BSZ * 64;
    }
    g.A[2] = g.A[1]; g.W[2] = g.W[1]; g.bias[2] = g.bias[1]; g.C[2] = g.C[1];
    hipLaunchKernelGGL((gemmb<0, 64, 0, 1>), dim3(1, 128, 2), dim3(256), 0, stream,
                       g, BSZ, 64, 64, 0);

    // ---- losses, batched over 3 ----
    hipLaunchKernelGGL(loss_b, dim3(256, 1, 3), dim3(256), 0, stream,
                       ZEP, ZQ, ATT, vq_loss, commit, 1.0f / (float)(BSZ * 64));

    // ---- decoders, batched over levels (plain bf16) ----
    for (int l = 0; l < 3; ++l) {
        g.A[l] = ZQ + (size_t)l * BSZ * 64; g.W[l] = dw1p[l];
        g.bias[l] = (const float*)d_in[3 + 13 * l + 7];
        g.C[l] = H1 + (size_t)l * BSZ * 256;
    }
    hipLaunchKernelGGL((gemmb<0, 128, 0, 1>), dim3(2, 128, 3), dim3(256), 0, stream,
                       g, BSZ, 256, 64, 1);
    for (int l = 0; l < 3; ++l) {
        g.A[l] = H1 + (size_t)l * BSZ * 256; g.W[l] = dw2p[l];
        g.bias[l] = (const float*)d_in[3 + 13 * l + 9];
        g.C[l] = H2 + (size_t)l * BSZ * 256;
    }
    hipLaunchKernelGGL((gemmb<0, 128, 0, 1>), dim3(2, 128, 3), dim3(256), 0, stream,
                       g, BSZ, 256, 256, 1);
    for (int l = 0; l < 3; ++l) {
        g.A[l] = H2 + (size_t)l * BSZ * 256; g.W[l] = dw3p[l];
        g.bias[l] = (const float*)d_in[3 + 13 * l + 11];
        g.C[l] = out + (size_t)l * BSZ * 512;
    }
    hipLaunchKernelGGL((gemmb<0, 128, 0, 0>), dim3(4, 128, 3), dim3(256), 0, stream,
                       g, BSZ, 512, 256, 0);
}